// Round 14
// baseline (7894.942 us; speedup 1.0000x reference)
//
#include <hip/hip_runtime.h>
#include <stdint.h>

// Predictive-coding inference: LAYER_SZS=[1024,4096,4096,4096,1024], B=2048, 5 iters.
// GEMM: C[M,N] = A[M,K](bf16) @ W[N,K](bf16)^T, f32 accum, fused epilogues.
// R14: add gemmW = 128x256 tile, 8 waves (2x4, each 64x64 out -- per-wave shape
// IDENTICAL to the proven gemm128: 16 ds_read_b128 + 32 MFMA/tile, 64 VGPR,
// same XOR swizzle), single-buffer 48KB LDS -> 3 blocks/CU. Each stage+barrier
// round serves 2x FLOPs at 1.5x staged bytes. E/P batches = exactly 768 blocks
// = 3.0/CU, zero tail. gemm128 retained for FF chain + standalone sig leg.
// Dead-leg pruning (R11) + sig-fold into P batch (R13) kept.

typedef __attribute__((ext_vector_type(8))) __bf16 bf16x8;
typedef __attribute__((ext_vector_type(4))) float f32x4;

#define B_ 2048

__device__ __forceinline__ unsigned short f2bf(float f) {
  union { float f; unsigned u; } v; v.f = f;
  unsigned u = v.u;
  u += 0x7FFFu + ((u >> 16) & 1u);
  return (unsigned short)(u >> 16);
}
__device__ __forceinline__ float bf2f(unsigned short s) {
  union { unsigned u; float f; } v; v.u = ((unsigned)s) << 16;
  return v.f;
}
__device__ __forceinline__ float fast_sig(float x) { return 1.0f / (1.0f + __expf(-x)); }
__device__ __forceinline__ float fast_tanh(float x) {
  return 1.0f - 2.0f / (__expf(2.0f * x) + 1.0f);
}
__device__ __forceinline__ void gload_lds16(const void* g, void* l) {
  __builtin_amdgcn_global_load_lds((const __attribute__((address_space(1))) void*)g,
                                   (__attribute__((address_space(3))) void*)l, 16, 0, 0);
}

// epilogue modes
#define M_ACT  0   // o0=t=tanh(acc); o1=relu(t)
#define M_ACTD 1   // + o2 = d = (relu(t)-t)(1-t^2)
#define M_SIG  2   // s=sig(acc); o0=(targ-s)s(1-s); fout=s
#define M_ERR  3   // o0(a) = relu(a + 0.1*acc - 0.1*(a - i0))
#define M_PRED 4   // t=tanh(acc); o0=t; o1=(i0 - t)(1-t^2)
#define M_PART 5   // fout[sk-plane] = acc (f32 partial sums, split-K)

struct GDesc {
  const unsigned short* A;   // [M,K]
  const unsigned short* W;   // [N,K]
  unsigned short* o0;
  unsigned short* o1;
  unsigned short* o2;
  const unsigned short* i0;
  const float* targ;
  float* fout;
  int K;     // row stride (elements)
  int knt;   // K-tiles (BK=64) per block
  int N, mode;
  int rm;    // remap flag for in-batch split-K sig leg
};

// ---- shared epilogue (both kernels; per-fragment 16x16, m89-verified layout) ----
#define EPILOGUE(MODE_, ROW_, COL_)                                              \
  if (MODE_ == M_ACT) {                                                          \
    _Pragma("unroll") for (int m = 0; m < 4; ++m)                                \
    _Pragma("unroll") for (int n = 0; n < 4; ++n)                                \
    _Pragma("unroll") for (int j = 0; j < 4; ++j) {                              \
      const size_t idx = (size_t)(ROW_) * N + (COL_);                            \
      float t = fast_tanh(acc[m][n][j]);                                         \
      d.o0[idx] = f2bf(t);                                                       \
      d.o1[idx] = f2bf(fmaxf(t, 0.f));                                           \
    }                                                                            \
  } else if (MODE_ == M_ACTD) {                                                  \
    _Pragma("unroll") for (int m = 0; m < 4; ++m)                                \
    _Pragma("unroll") for (int n = 0; n < 4; ++n)                                \
    _Pragma("unroll") for (int j = 0; j < 4; ++j) {                              \
      const size_t idx = (size_t)(ROW_) * N + (COL_);                            \
      float t = fast_tanh(acc[m][n][j]);                                         \
      d.o0[idx] = f2bf(t);                                                       \
      d.o1[idx] = f2bf(fmaxf(t, 0.f));                                           \
      d.o2[idx] = f2bf(t >= 0.f ? 0.f : (-t) * (1.f - t * t));                   \
    }                                                                            \
  } else if (MODE_ == M_SIG) {                                                   \
    _Pragma("unroll") for (int m = 0; m < 4; ++m)                                \
    _Pragma("unroll") for (int n = 0; n < 4; ++n)                                \
    _Pragma("unroll") for (int j = 0; j < 4; ++j) {                              \
      const size_t idx = (size_t)(ROW_) * N + (COL_);                            \
      float s = fast_sig(acc[m][n][j]);                                          \
      d.fout[idx] = s;                                                           \
      d.o0[idx] = f2bf((d.targ[idx] - s) * s * (1.f - s));                       \
    }                                                                            \
  } else if (MODE_ == M_ERR) {                                                   \
    _Pragma("unroll") for (int m = 0; m < 4; ++m)                                \
    _Pragma("unroll") for (int n = 0; n < 4; ++n)                                \
    _Pragma("unroll") for (int j = 0; j < 4; ++j) {                              \
      const size_t idx = (size_t)(ROW_) * N + (COL_);                            \
      float a = bf2f(d.o0[idx]);                                                 \
      float tp = bf2f(d.i0[idx]);                                                \
      d.o0[idx] = f2bf(fmaxf(a + 0.1f * acc[m][n][j] - 0.1f * (a - tp), 0.f));   \
    }                                                                            \
  } else if (MODE_ == M_PRED) {                                                  \
    _Pragma("unroll") for (int m = 0; m < 4; ++m)                                \
    _Pragma("unroll") for (int n = 0; n < 4; ++n)                                \
    _Pragma("unroll") for (int j = 0; j < 4; ++j) {                              \
      const size_t idx = (size_t)(ROW_) * N + (COL_);                            \
      float t = fast_tanh(acc[m][n][j]);                                         \
      d.o0[idx] = f2bf(t);                                                       \
      float an = bf2f(d.i0[idx]);                                                \
      d.o1[idx] = f2bf((an - t) * (1.f - t * t));                                \
    }                                                                            \
  } else {                                                                       \
    float* po = d.fout + (size_t)sk * 2048 * N;                                  \
    _Pragma("unroll") for (int m = 0; m < 4; ++m)                                \
    _Pragma("unroll") for (int n = 0; n < 4; ++n)                                \
    _Pragma("unroll") for (int j = 0; j < 4; ++j) {                              \
      const size_t idx = (size_t)(ROW_) * N + (COL_);                            \
      po[idx] = acc[m][n][j];                                                    \
    }                                                                            \
  }

// ===================== gemmW: 128x256, 8 waves, single-buffer ====================
__global__ __launch_bounds__(512, 6) void gemmW(GDesc d0, GDesc d1, GDesc d2) {
  const GDesc d = (blockIdx.z == 0) ? d0 : (blockIdx.z == 1 ? d1 : d2);

  __shared__ alignas(16) unsigned short As[128 * 64];
  __shared__ alignas(16) unsigned short Bs[256 * 64];

  const int tid = threadIdx.x;
  const int wid = tid >> 6, lane = tid & 63;
  const int wr = wid >> 2, wc = wid & 3;      // 2 x 4 waves, 64x64 out each
  const int q = lane >> 4, j16 = lane & 15, r3 = j16 & 7;
  const int K = d.K, N = d.N, nt = d.knt;

  int bx, by, sk;
  if (d.rm) {  // split-K sig leg packed in a (16,16) grid layer: N=1024, KS=4
    const int lid = blockIdx.y * 16 + blockIdx.x;
    bx = lid & 3; by = (lid >> 2) & 15; sk = lid >> 6;
  } else {
    bx = blockIdx.x; by = blockIdx.y; sk = 0;
  }
  const int row0 = by << 7;                   // BM = 128
  const int col0 = bx << 8;                   // BN = 256
  const int kbeg = (sk * nt) << 6;

  const int rbase = (wid << 3) + (lane >> 3);                 // 0..63
  const int csw   = ((lane & 7) ^ ((lane >> 3) & 7)) << 3;    // swizzled chunk
  const unsigned short* Ag = d.A + (size_t)row0 * K;
  const unsigned short* Bg = d.W + (size_t)col0 * K;
  const int ldst = wid << 9;

  int aoff[4][2], boff[4][2];
#pragma unroll
  for (int m = 0; m < 4; ++m)
#pragma unroll
    for (int ks = 0; ks < 2; ++ks) {
      aoff[m][ks] = (wr * 64 + m * 16 + j16) * 64 + (((ks * 4 + q) ^ r3) << 3);
      boff[m][ks] = (wc * 64 + m * 16 + j16) * 64 + (((ks * 4 + q) ^ r3) << 3);
    }

  f32x4 acc[4][4];
#pragma unroll
  for (int m = 0; m < 4; ++m)
#pragma unroll
    for (int n = 0; n < 4; ++n) acc[m][n] = (f32x4){0.f, 0.f, 0.f, 0.f};

  for (int t = 0; t < nt; ++t) {
    const int k0 = kbeg + (t << 6);
#pragma unroll
    for (int i = 0; i < 2; ++i)   // A: 128 rows in 2 passes of 64
      gload_lds16(Ag + (size_t)((i << 6) + rbase) * K + k0 + csw,
                  As + (i << 12) + ldst);
#pragma unroll
    for (int i = 0; i < 4; ++i)   // B: 256 rows in 4 passes of 64
      gload_lds16(Bg + (size_t)((i << 6) + rbase) * K + k0 + csw,
                  Bs + (i << 12) + ldst);
    asm volatile("s_waitcnt vmcnt(0)" ::: "memory");
    __builtin_amdgcn_s_barrier();

#pragma unroll
    for (int ks = 0; ks < 2; ++ks) {
      bf16x8 av[4], bv[4];
#pragma unroll
      for (int m = 0; m < 4; ++m) av[m] = *(const bf16x8*)(As + aoff[m][ks]);
#pragma unroll
      for (int n = 0; n < 4; ++n) bv[n] = *(const bf16x8*)(Bs + boff[n][ks]);
#pragma unroll
      for (int m = 0; m < 4; ++m)
#pragma unroll
        for (int n = 0; n < 4; ++n)
          acc[m][n] = __builtin_amdgcn_mfma_f32_16x16x32_bf16(av[m], bv[n], acc[m][n], 0, 0, 0);
    }
    __builtin_amdgcn_s_barrier();
  }

  EPILOGUE(d.mode,
           row0 + wr * 64 + m * 16 + (q << 2) + j,
           col0 + wc * 64 + n * 16 + j16)
}

// ===================== gemm128: 128x128, 4 waves (R13, proven) ===================
__global__ __launch_bounds__(256, 4) void gemm128(GDesc d0, GDesc d1, GDesc d2) {
  const GDesc d = (blockIdx.z == 0) ? d0 : (blockIdx.z == 1 ? d1 : d2);

  __shared__ alignas(16) unsigned short As[128 * 64];
  __shared__ alignas(16) unsigned short Bs[128 * 64];

  const int tid = threadIdx.x;
  const int wid = tid >> 6, lane = tid & 63;
  const int wr = wid >> 1, wc = wid & 1;      // 2 x 2 waves
  const int q = lane >> 4, j16 = lane & 15, r3 = j16 & 7;
  const int K = d.K, N = d.N, nt = d.knt;

  const int bx = blockIdx.x, by = blockIdx.y & 15, sk = blockIdx.y >> 4;
  const int row0 = by << 7;                   // BM = 128
  const int col0 = bx << 7;                   // BN = 128
  const int kbeg = (sk * nt) << 6;

  const int rbase = (wid << 3) + (lane >> 3);                 // 0..31
  const int csw   = ((lane & 7) ^ ((lane >> 3) & 7)) << 3;
  const unsigned short* Ag = d.A + (size_t)row0 * K;
  const unsigned short* Bg = d.W + (size_t)col0 * K;
  const int ldst = wid << 9;

  int aoff[4][2], boff[4][2];
#pragma unroll
  for (int m = 0; m < 4; ++m)
#pragma unroll
    for (int ks = 0; ks < 2; ++ks) {
      aoff[m][ks] = (wr * 64 + m * 16 + j16) * 64 + (((ks * 4 + q) ^ r3) << 3);
      boff[m][ks] = (wc * 64 + m * 16 + j16) * 64 + (((ks * 4 + q) ^ r3) << 3);
    }

  f32x4 acc[4][4];
#pragma unroll
  for (int m = 0; m < 4; ++m)
#pragma unroll
    for (int n = 0; n < 4; ++n) acc[m][n] = (f32x4){0.f, 0.f, 0.f, 0.f};

  for (int t = 0; t < nt; ++t) {
    const int k0 = kbeg + (t << 6);
#pragma unroll
    for (int i = 0; i < 4; ++i)
      gload_lds16(Ag + (size_t)((i << 5) + rbase) * K + k0 + csw,
                  As + (i << 11) + ldst);
#pragma unroll
    for (int i = 0; i < 4; ++i)
      gload_lds16(Bg + (size_t)((i << 5) + rbase) * K + k0 + csw,
                  Bs + (i << 11) + ldst);
    asm volatile("s_waitcnt vmcnt(0)" ::: "memory");
    __builtin_amdgcn_s_barrier();

#pragma unroll
    for (int ks = 0; ks < 2; ++ks) {
      bf16x8 av[4], bv[4];
#pragma unroll
      for (int m = 0; m < 4; ++m) av[m] = *(const bf16x8*)(As + aoff[m][ks]);
#pragma unroll
      for (int n = 0; n < 4; ++n) bv[n] = *(const bf16x8*)(Bs + boff[n][ks]);
#pragma unroll
      for (int m = 0; m < 4; ++m)
#pragma unroll
        for (int n = 0; n < 4; ++n)
          acc[m][n] = __builtin_amdgcn_mfma_f32_16x16x32_bf16(av[m], bv[n], acc[m][n], 0, 0, 0);
    }
    __builtin_amdgcn_s_barrier();
  }

  EPILOGUE(d.mode,
           row0 + wr * 64 + m * 16 + (q << 2) + j,
           col0 + wc * 64 + n * 16 + j16)
}

// ---------------- split-K combine: sum partials -> sigmoid -> d3, out ----------
__global__ void k_comb(const float* __restrict__ psum, const float* __restrict__ targ,
                       unsigned short* __restrict__ d3, float* __restrict__ out,
                       int n4, int ks) {
  const size_t plane4 = (size_t)2048 * 1024 / 4;
  int i = blockIdx.x * blockDim.x + threadIdx.x, st = gridDim.x * blockDim.x;
  for (; i < n4; i += st) {
    float4 s0 = ((const float4*)psum)[i];
    for (int s = 1; s < ks; ++s) {
      float4 sv = ((const float4*)psum)[i + s * plane4];
      s0.x += sv.x; s0.y += sv.y; s0.z += sv.z; s0.w += sv.w;
    }
    float4 tv = ((const float4*)targ)[i];
    float4 o; ushort4 dv; float sg;
    sg = fast_sig(s0.x); o.x = sg; dv.x = f2bf((tv.x - sg) * sg * (1.f - sg));
    sg = fast_sig(s0.y); o.y = sg; dv.y = f2bf((tv.y - sg) * sg * (1.f - sg));
    sg = fast_sig(s0.z); o.z = sg; dv.z = f2bf((tv.z - sg) * sg * (1.f - sg));
    sg = fast_sig(s0.w); o.w = sg; dv.w = f2bf((tv.w - sg) * sg * (1.f - sg));
    ((float4*)out)[i] = o;
    ((ushort4*)d3)[i] = dv;
  }
}

// ---------------- batched f32 -> bf16 conversion (8 jobs, one launch) ----------
struct CvtJobs {
  const float* src[8];
  unsigned short* dst[8];
  int n4[8];
};
__global__ void k_cvt8(CvtJobs J) {
  const int jb = blockIdx.y;
  const float* s = J.src[jb];
  unsigned short* dd = J.dst[jb];
  const int n4 = J.n4[jb];
  int i = blockIdx.x * blockDim.x + threadIdx.x, st = gridDim.x * blockDim.x;
  for (; i < n4; i += st) {
    float4 v = ((const float4*)s)[i];
    ushort4 o; o.x = f2bf(v.x); o.y = f2bf(v.y); o.z = f2bf(v.z); o.w = f2bf(v.w);
    ((ushort4*)dd)[i] = o;
  }
}

// ------------------------------------------------------------------------------------
extern "C" void kernel_launch(void* const* d_in, const int* in_sizes, int n_in,
                              void* d_out, int out_size, void* d_ws, size_t ws_size,
                              hipStream_t stream) {
  (void)in_sizes; (void)n_in; (void)out_size;
  const float* x      = (const float*)d_in[0];
  const float* target = (const float*)d_in[1];
  const float* wSrc[7] = {(const float*)d_in[2], (const float*)d_in[3],
                          (const float*)d_in[4], (const float*)d_in[5],
                          (const float*)d_in[6], (const float*)d_in[7],
                          (const float*)d_in[8]};
  const size_t wN[7] = {(size_t)4096 * 1024, (size_t)4096 * 4096, (size_t)4096 * 4096,
                        (size_t)1024 * 4096, (size_t)4096 * 4096, (size_t)4096 * 4096,
                        (size_t)4096 * 1024};

  char* w = (char*)d_ws;
  size_t off = 0;
  auto alloc = [&](size_t bytes) { void* p = w + off; off += bytes; return p; };

  const size_t BIG = (size_t)B_ * 4096;
  const size_t SML = (size_t)B_ * 1024;
  unsigned short* xb  = (unsigned short*)alloc(SML * 2);
  unsigned short* a1b = (unsigned short*)alloc(BIG * 2);
  unsigned short* a2b = (unsigned short*)alloc(BIG * 2);
  unsigned short* a3b = (unsigned short*)alloc(BIG * 2);
  unsigned short* t0b = (unsigned short*)alloc(BIG * 2);
  unsigned short* t1b = (unsigned short*)alloc(BIG * 2);
  unsigned short* t2b = (unsigned short*)alloc(BIG * 2);
  unsigned short* d1b = (unsigned short*)alloc(BIG * 2);
  unsigned short* d2b = (unsigned short*)alloc(BIG * 2);
  unsigned short* d3b = (unsigned short*)alloc(SML * 2);
  unsigned short* Wb[7];
  for (int i = 0; i < 7; ++i) Wb[i] = (unsigned short*)alloc(wN[i] * 2);

  // split-K partials for the N=1024 legs
  const size_t PS = SML * 4;  // 8 MB per plane
  int KS = 1;
  if (ws_size >= off + 4 * PS) KS = 4;
  else if (ws_size >= off + 2 * PS) KS = 2;
  float* psum = (KS > 1) ? (float*)alloc((size_t)KS * PS) : nullptr;

  // ---- conversions: one batched launch ----
  CvtJobs J;
  for (int i = 0; i < 7; ++i) { J.src[i] = wSrc[i]; J.dst[i] = Wb[i]; J.n4[i] = (int)(wN[i] >> 2); }
  J.src[7] = x; J.dst[7] = xb; J.n4[7] = (int)(SML >> 2);
  k_cvt8<<<dim3(2048, 8), 256, 0, stream>>>(J);

  float* out = (float*)d_out;
  const int n4_sml = (int)(SML >> 2);
  auto desc = [&](const unsigned short* A, const unsigned short* W_, int K, int knt,
                  int N, int mode, unsigned short* o0, unsigned short* o1,
                  unsigned short* o2, const unsigned short* i0, const float* targ,
                  float* fout, int rm) {
    GDesc g; g.A = A; g.W = W_; g.o0 = o0; g.o1 = o1; g.o2 = o2; g.i0 = i0;
    g.targ = targ; g.fout = fout; g.K = K; g.knt = knt; g.N = N; g.mode = mode;
    g.rm = rm;
    return g;
  };
  auto sig_desc = [&](const unsigned short* A, int rm) {
    if (KS > 1)
      return desc(A, Wb[3], 4096, 64 / KS, 1024, M_PART,
                  nullptr, nullptr, nullptr, nullptr, nullptr, psum, rm);
    return desc(A, Wb[3], 4096, 64, 1024, M_SIG,
                d3b, nullptr, nullptr, nullptr, target, out, rm);
  };
  auto sig_standalone = [&](const unsigned short* A) {
    if (KS > 1) {
      GDesc g = sig_desc(A, 0);
      gemm128<<<dim3(8, 16 * KS, 1), 256, 0, stream>>>(g, g, g);
      k_comb<<<2048, 256, 0, stream>>>(psum, target, d3b, out, n4_sml, KS);
    } else {
      GDesc g = sig_desc(A, 0);
      gemm128<<<dim3(8, 16, 1), 256, 0, stream>>>(g, g, g);
    }
  };

  // ---- initial feedforward (gemm128: sequential chain, 512-block grids) ----
  {
    GDesc g0 = desc(xb,  Wb[0], 1024, 16, 4096, M_ACT,  t0b, a1b, nullptr, nullptr, nullptr, nullptr, 0);
    gemm128<<<dim3(32, 16, 1), 256, 0, stream>>>(g0, g0, g0);
    GDesc g1 = desc(a1b, Wb[1], 4096, 64, 4096, M_ACTD, t1b, a2b, d1b, nullptr, nullptr, nullptr, 0);
    gemm128<<<dim3(32, 16, 1), 256, 0, stream>>>(g1, g1, g1);
    GDesc g2 = desc(a2b, Wb[2], 4096, 64, 4096, M_ACTD, t2b, a3b, d2b, nullptr, nullptr, nullptr, 0);
    gemm128<<<dim3(32, 16, 1), 256, 0, stream>>>(g2, g2, g2);
    sig_standalone(a3b);
  }

  // ---- 5 inference iterations (gemmW batches; dead-leg pruning) ----
  for (int it = 1; it <= 5; ++it) {
    GDesc e0 = desc(d1b, Wb[4], 4096, 64, 4096, M_ERR, a1b, nullptr, nullptr, t0b, nullptr, nullptr, 0);
    GDesc e1 = desc(d2b, Wb[5], 4096, 64, 4096, M_ERR, a2b, nullptr, nullptr, t1b, nullptr, nullptr, 0);
    GDesc e2 = desc(d3b, Wb[6], 1024, 16, 4096, M_ERR, a3b, nullptr, nullptr, t2b, nullptr, nullptr, 0);
    GDesc p0 = desc(a1b, Wb[1], 4096, 64, 4096, M_PRED, t1b, d1b, nullptr, a2b, nullptr, nullptr, 0);
    GDesc p1 = desc(a2b, Wb[2], 4096, 64, 4096, M_PRED, t2b, d2b, nullptr, a3b, nullptr, nullptr, 0);
    if (it <= 3) {
      gemmW<<<dim3(16, 16, 3), 512, 0, stream>>>(e0, e1, e2);   // 768 blk = 3/CU
      if (KS == 4) {
        GDesc sg = sig_desc(a3b, 1);
        gemmW<<<dim3(16, 16, 3), 512, 0, stream>>>(p0, p1, sg); // 768 blk
        k_comb<<<2048, 256, 0, stream>>>(psum, target, d3b, out, n4_sml, KS);
      } else {
        gemmW<<<dim3(16, 16, 2), 512, 0, stream>>>(p0, p1, p1);
        sig_standalone(a3b);
      }
    } else if (it == 4) {
      // e0 dead (a1_4 only feeds dead p0_4); p0 dead (t1_4/d1_4 feed dead legs)
      gemmW<<<dim3(16, 16, 2), 512, 0, stream>>>(e1, e2, e2);
      if (KS == 4) {
        GDesc sg = sig_desc(a3b, 1);
        gemmW<<<dim3(16, 16, 2), 512, 0, stream>>>(p1, sg, sg);
        k_comb<<<2048, 256, 0, stream>>>(psum, target, d3b, out, n4_sml, KS);
      } else {
        gemmW<<<dim3(16, 16, 1), 512, 0, stream>>>(p1, p1, p1);
        sig_standalone(a3b);
      }
    } else {
      // iter 5: only a3 update + final output leg live
      gemmW<<<dim3(16, 16, 1), 512, 0, stream>>>(e2, e2, e2);
      sig_standalone(a3b);
    }
  }
}

// Round 15
// 1654.673 us; speedup vs baseline: 4.7713x; 4.7713x over previous
//
#include <hip/hip_runtime.h>
#include <stdint.h>

// Predictive-coding inference: LAYER_SZS=[1024,4096,4096,4096,1024], B=2048, 5 iters.
// GEMM: C[M,N] = A[M,K](bf16) @ W[N,K](bf16)^T, f32 accum, fused epilogues.
// R15: gemmW (128x256, 8 waves, 48KB LDS) re-tried with __launch_bounds__(512,2)
// -- R14's (512,6) forced an ~85-VGPR cap -> accumulator SPILLED to scratch
// (VGPR 40, FETCH 1.59GB, 5.8% MfmaUtil). With cap 256: no spill, 2 blocks/CU
// (4 waves/SIMD), same per-wave work as gemm128 but 2x FLOPs per barrier round
// and 6KB vs 8KB staged per wave-tile. Used ONLY for exact-512-block pairs
// {e0,e1}, {p0,p1}. e2 + split-K sig stay on proven gemm128 (R13 = 1751us
// fallback). Dead-leg pruning kept. M_ERR legs are read-modify-write: never
// duplicate a descriptor across z.

typedef __attribute__((ext_vector_type(8))) __bf16 bf16x8;
typedef __attribute__((ext_vector_type(4))) float f32x4;

#define B_ 2048

__device__ __forceinline__ unsigned short f2bf(float f) {
  union { float f; unsigned u; } v; v.f = f;
  unsigned u = v.u;
  u += 0x7FFFu + ((u >> 16) & 1u);
  return (unsigned short)(u >> 16);
}
__device__ __forceinline__ float bf2f(unsigned short s) {
  union { unsigned u; float f; } v; v.u = ((unsigned)s) << 16;
  return v.f;
}
__device__ __forceinline__ float fast_sig(float x) { return 1.0f / (1.0f + __expf(-x)); }
__device__ __forceinline__ float fast_tanh(float x) {
  return 1.0f - 2.0f / (__expf(2.0f * x) + 1.0f);
}
__device__ __forceinline__ void gload_lds16(const void* g, void* l) {
  __builtin_amdgcn_global_load_lds((const __attribute__((address_space(1))) void*)g,
                                   (__attribute__((address_space(3))) void*)l, 16, 0, 0);
}

// epilogue modes
#define M_ACT  0   // o0=t=tanh(acc); o1=relu(t)
#define M_ACTD 1   // + o2 = d = (relu(t)-t)(1-t^2)
#define M_SIG  2   // s=sig(acc); o0=(targ-s)s(1-s); fout=s
#define M_ERR  3   // o0(a) = relu(a + 0.1*acc - 0.1*(a - i0))
#define M_PRED 4   // t=tanh(acc); o0=t; o1=(i0 - t)(1-t^2)
#define M_PART 5   // fout[sk-plane] = acc (f32 partial sums, split-K)

struct GDesc {
  const unsigned short* A;   // [M,K]
  const unsigned short* W;   // [N,K]
  unsigned short* o0;
  unsigned short* o1;
  unsigned short* o2;
  const unsigned short* i0;
  const float* targ;
  float* fout;
  int K;     // row stride (elements)
  int knt;   // K-tiles (BK=64) per block
  int N, mode;
};

// ---- shared epilogue (per-fragment 16x16, m89-verified layout) ----
#define EPILOGUE(MODE_, ROW_, COL_)                                              \
  if (MODE_ == M_ACT) {                                                          \
    _Pragma("unroll") for (int m = 0; m < 4; ++m)                                \
    _Pragma("unroll") for (int n = 0; n < 4; ++n)                                \
    _Pragma("unroll") for (int j = 0; j < 4; ++j) {                              \
      const size_t idx = (size_t)(ROW_) * N + (COL_);                            \
      float t = fast_tanh(acc[m][n][j]);                                         \
      d.o0[idx] = f2bf(t);                                                       \
      d.o1[idx] = f2bf(fmaxf(t, 0.f));                                           \
    }                                                                            \
  } else if (MODE_ == M_ACTD) {                                                  \
    _Pragma("unroll") for (int m = 0; m < 4; ++m)                                \
    _Pragma("unroll") for (int n = 0; n < 4; ++n)                                \
    _Pragma("unroll") for (int j = 0; j < 4; ++j) {                              \
      const size_t idx = (size_t)(ROW_) * N + (COL_);                            \
      float t = fast_tanh(acc[m][n][j]);                                         \
      d.o0[idx] = f2bf(t);                                                       \
      d.o1[idx] = f2bf(fmaxf(t, 0.f));                                           \
      d.o2[idx] = f2bf(t >= 0.f ? 0.f : (-t) * (1.f - t * t));                   \
    }                                                                            \
  } else if (MODE_ == M_SIG) {                                                   \
    _Pragma("unroll") for (int m = 0; m < 4; ++m)                                \
    _Pragma("unroll") for (int n = 0; n < 4; ++n)                                \
    _Pragma("unroll") for (int j = 0; j < 4; ++j) {                              \
      const size_t idx = (size_t)(ROW_) * N + (COL_);                            \
      float s = fast_sig(acc[m][n][j]);                                          \
      d.fout[idx] = s;                                                           \
      d.o0[idx] = f2bf((d.targ[idx] - s) * s * (1.f - s));                       \
    }                                                                            \
  } else if (MODE_ == M_ERR) {                                                   \
    _Pragma("unroll") for (int m = 0; m < 4; ++m)                                \
    _Pragma("unroll") for (int n = 0; n < 4; ++n)                                \
    _Pragma("unroll") for (int j = 0; j < 4; ++j) {                              \
      const size_t idx = (size_t)(ROW_) * N + (COL_);                            \
      float a = bf2f(d.o0[idx]);                                                 \
      float tp = bf2f(d.i0[idx]);                                                \
      d.o0[idx] = f2bf(fmaxf(a + 0.1f * acc[m][n][j] - 0.1f * (a - tp), 0.f));   \
    }                                                                            \
  } else if (MODE_ == M_PRED) {                                                  \
    _Pragma("unroll") for (int m = 0; m < 4; ++m)                                \
    _Pragma("unroll") for (int n = 0; n < 4; ++n)                                \
    _Pragma("unroll") for (int j = 0; j < 4; ++j) {                              \
      const size_t idx = (size_t)(ROW_) * N + (COL_);                            \
      float t = fast_tanh(acc[m][n][j]);                                         \
      d.o0[idx] = f2bf(t);                                                       \
      float an = bf2f(d.i0[idx]);                                                \
      d.o1[idx] = f2bf((an - t) * (1.f - t * t));                                \
    }                                                                            \
  } else {                                                                       \
    float* po = d.fout + (size_t)sk * 2048 * N;                                  \
    _Pragma("unroll") for (int m = 0; m < 4; ++m)                                \
    _Pragma("unroll") for (int n = 0; n < 4; ++n)                                \
    _Pragma("unroll") for (int j = 0; j < 4; ++j) {                              \
      const size_t idx = (size_t)(ROW_) * N + (COL_);                            \
      po[idx] = acc[m][n][j];                                                    \
    }                                                                            \
  }

// ===================== gemmW: 128x256, 8 waves, single-buffer ====================
__global__ __launch_bounds__(512, 2) void gemmW(GDesc d0, GDesc d1) {
  const GDesc d = (blockIdx.z == 0) ? d0 : d1;

  __shared__ alignas(16) unsigned short As[128 * 64];
  __shared__ alignas(16) unsigned short Bs[256 * 64];

  const int tid = threadIdx.x;
  const int wid = tid >> 6, lane = tid & 63;
  const int wr = wid >> 2, wc = wid & 3;      // 2 x 4 waves, 64x64 out each
  const int q = lane >> 4, j16 = lane & 15, r3 = j16 & 7;
  const int K = d.K, N = d.N, nt = d.knt;
  const int sk = 0;
  (void)sk;

  const int row0 = blockIdx.y << 7;           // BM = 128
  const int col0 = blockIdx.x << 8;           // BN = 256

  const int rbase = (wid << 3) + (lane >> 3);                 // 0..63
  const int csw   = ((lane & 7) ^ ((lane >> 3) & 7)) << 3;    // swizzled chunk
  const unsigned short* Ag = d.A + (size_t)row0 * K;
  const unsigned short* Bg = d.W + (size_t)col0 * K;
  const int ldst = wid << 9;

  int aoff[4][2], boff[4][2];
#pragma unroll
  for (int m = 0; m < 4; ++m)
#pragma unroll
    for (int ks = 0; ks < 2; ++ks) {
      aoff[m][ks] = (wr * 64 + m * 16 + j16) * 64 + (((ks * 4 + q) ^ r3) << 3);
      boff[m][ks] = (wc * 64 + m * 16 + j16) * 64 + (((ks * 4 + q) ^ r3) << 3);
    }

  f32x4 acc[4][4];
#pragma unroll
  for (int m = 0; m < 4; ++m)
#pragma unroll
    for (int n = 0; n < 4; ++n) acc[m][n] = (f32x4){0.f, 0.f, 0.f, 0.f};

  for (int t = 0; t < nt; ++t) {
    const int k0 = t << 6;
#pragma unroll
    for (int i = 0; i < 2; ++i)   // A: 128 rows in 2 passes of 64
      gload_lds16(Ag + (size_t)((i << 6) + rbase) * K + k0 + csw,
                  As + (i << 12) + ldst);
#pragma unroll
    for (int i = 0; i < 4; ++i)   // B: 256 rows in 4 passes of 64
      gload_lds16(Bg + (size_t)((i << 6) + rbase) * K + k0 + csw,
                  Bs + (i << 12) + ldst);
    asm volatile("s_waitcnt vmcnt(0)" ::: "memory");
    __builtin_amdgcn_s_barrier();

#pragma unroll
    for (int ks = 0; ks < 2; ++ks) {
      bf16x8 av[4], bv[4];
#pragma unroll
      for (int m = 0; m < 4; ++m) av[m] = *(const bf16x8*)(As + aoff[m][ks]);
#pragma unroll
      for (int n = 0; n < 4; ++n) bv[n] = *(const bf16x8*)(Bs + boff[n][ks]);
#pragma unroll
      for (int m = 0; m < 4; ++m)
#pragma unroll
        for (int n = 0; n < 4; ++n)
          acc[m][n] = __builtin_amdgcn_mfma_f32_16x16x32_bf16(av[m], bv[n], acc[m][n], 0, 0, 0);
    }
    __builtin_amdgcn_s_barrier();
  }

  EPILOGUE(d.mode,
           row0 + wr * 64 + m * 16 + (q << 2) + j,
           col0 + wc * 64 + n * 16 + j16)
}

// ===================== gemm128: 128x128, 4 waves (R13, proven) ===================
__global__ __launch_bounds__(256, 4) void gemm128(GDesc d0, GDesc d1, GDesc d2) {
  const GDesc d = (blockIdx.z == 0) ? d0 : (blockIdx.z == 1 ? d1 : d2);

  __shared__ alignas(16) unsigned short As[128 * 64];
  __shared__ alignas(16) unsigned short Bs[128 * 64];

  const int tid = threadIdx.x;
  const int wid = tid >> 6, lane = tid & 63;
  const int wr = wid >> 1, wc = wid & 1;      // 2 x 2 waves
  const int q = lane >> 4, j16 = lane & 15, r3 = j16 & 7;
  const int K = d.K, N = d.N, nt = d.knt;

  const int bx = blockIdx.x, by = blockIdx.y & 15, sk = blockIdx.y >> 4;
  const int row0 = by << 7;                   // BM = 128
  const int col0 = bx << 7;                   // BN = 128
  const int kbeg = (sk * nt) << 6;

  const int rbase = (wid << 3) + (lane >> 3);                 // 0..31
  const int csw   = ((lane & 7) ^ ((lane >> 3) & 7)) << 3;
  const unsigned short* Ag = d.A + (size_t)row0 * K;
  const unsigned short* Bg = d.W + (size_t)col0 * K;
  const int ldst = wid << 9;

  int aoff[4][2], boff[4][2];
#pragma unroll
  for (int m = 0; m < 4; ++m)
#pragma unroll
    for (int ks = 0; ks < 2; ++ks) {
      aoff[m][ks] = (wr * 64 + m * 16 + j16) * 64 + (((ks * 4 + q) ^ r3) << 3);
      boff[m][ks] = (wc * 64 + m * 16 + j16) * 64 + (((ks * 4 + q) ^ r3) << 3);
    }

  f32x4 acc[4][4];
#pragma unroll
  for (int m = 0; m < 4; ++m)
#pragma unroll
    for (int n = 0; n < 4; ++n) acc[m][n] = (f32x4){0.f, 0.f, 0.f, 0.f};

  for (int t = 0; t < nt; ++t) {
    const int k0 = kbeg + (t << 6);
#pragma unroll
    for (int i = 0; i < 4; ++i)
      gload_lds16(Ag + (size_t)((i << 5) + rbase) * K + k0 + csw,
                  As + (i << 11) + ldst);
#pragma unroll
    for (int i = 0; i < 4; ++i)
      gload_lds16(Bg + (size_t)((i << 5) + rbase) * K + k0 + csw,
                  Bs + (i << 11) + ldst);
    asm volatile("s_waitcnt vmcnt(0)" ::: "memory");
    __builtin_amdgcn_s_barrier();

#pragma unroll
    for (int ks = 0; ks < 2; ++ks) {
      bf16x8 av[4], bv[4];
#pragma unroll
      for (int m = 0; m < 4; ++m) av[m] = *(const bf16x8*)(As + aoff[m][ks]);
#pragma unroll
      for (int n = 0; n < 4; ++n) bv[n] = *(const bf16x8*)(Bs + boff[n][ks]);
#pragma unroll
      for (int m = 0; m < 4; ++m)
#pragma unroll
        for (int n = 0; n < 4; ++n)
          acc[m][n] = __builtin_amdgcn_mfma_f32_16x16x32_bf16(av[m], bv[n], acc[m][n], 0, 0, 0);
    }
    __builtin_amdgcn_s_barrier();
  }

  EPILOGUE(d.mode,
           row0 + wr * 64 + m * 16 + (q << 2) + j,
           col0 + wc * 64 + n * 16 + j16)
}

// ---------------- split-K combine: sum partials -> sigmoid -> d3, out ----------
__global__ void k_comb(const float* __restrict__ psum, const float* __restrict__ targ,
                       unsigned short* __restrict__ d3, float* __restrict__ out,
                       int n4, int ks) {
  const size_t plane4 = (size_t)2048 * 1024 / 4;
  int i = blockIdx.x * blockDim.x + threadIdx.x, st = gridDim.x * blockDim.x;
  for (; i < n4; i += st) {
    float4 s0 = ((const float4*)psum)[i];
    for (int s = 1; s < ks; ++s) {
      float4 sv = ((const float4*)psum)[i + s * plane4];
      s0.x += sv.x; s0.y += sv.y; s0.z += sv.z; s0.w += sv.w;
    }
    float4 tv = ((const float4*)targ)[i];
    float4 o; ushort4 dv; float sg;
    sg = fast_sig(s0.x); o.x = sg; dv.x = f2bf((tv.x - sg) * sg * (1.f - sg));
    sg = fast_sig(s0.y); o.y = sg; dv.y = f2bf((tv.y - sg) * sg * (1.f - sg));
    sg = fast_sig(s0.z); o.z = sg; dv.z = f2bf((tv.z - sg) * sg * (1.f - sg));
    sg = fast_sig(s0.w); o.w = sg; dv.w = f2bf((tv.w - sg) * sg * (1.f - sg));
    ((float4*)out)[i] = o;
    ((ushort4*)d3)[i] = dv;
  }
}

// ---------------- batched f32 -> bf16 conversion (8 jobs, one launch) ----------
struct CvtJobs {
  const float* src[8];
  unsigned short* dst[8];
  int n4[8];
};
__global__ void k_cvt8(CvtJobs J) {
  const int jb = blockIdx.y;
  const float* s = J.src[jb];
  unsigned short* dd = J.dst[jb];
  const int n4 = J.n4[jb];
  int i = blockIdx.x * blockDim.x + threadIdx.x, st = gridDim.x * blockDim.x;
  for (; i < n4; i += st) {
    float4 v = ((const float4*)s)[i];
    ushort4 o; o.x = f2bf(v.x); o.y = f2bf(v.y); o.z = f2bf(v.z); o.w = f2bf(v.w);
    ((ushort4*)dd)[i] = o;
  }
}

// ------------------------------------------------------------------------------------
extern "C" void kernel_launch(void* const* d_in, const int* in_sizes, int n_in,
                              void* d_out, int out_size, void* d_ws, size_t ws_size,
                              hipStream_t stream) {
  (void)in_sizes; (void)n_in; (void)out_size;
  const float* x      = (const float*)d_in[0];
  const float* target = (const float*)d_in[1];
  const float* wSrc[7] = {(const float*)d_in[2], (const float*)d_in[3],
                          (const float*)d_in[4], (const float*)d_in[5],
                          (const float*)d_in[6], (const float*)d_in[7],
                          (const float*)d_in[8]};
  const size_t wN[7] = {(size_t)4096 * 1024, (size_t)4096 * 4096, (size_t)4096 * 4096,
                        (size_t)1024 * 4096, (size_t)4096 * 4096, (size_t)4096 * 4096,
                        (size_t)4096 * 1024};

  char* w = (char*)d_ws;
  size_t off = 0;
  auto alloc = [&](size_t bytes) { void* p = w + off; off += bytes; return p; };

  const size_t BIG = (size_t)B_ * 4096;
  const size_t SML = (size_t)B_ * 1024;
  unsigned short* xb  = (unsigned short*)alloc(SML * 2);
  unsigned short* a1b = (unsigned short*)alloc(BIG * 2);
  unsigned short* a2b = (unsigned short*)alloc(BIG * 2);
  unsigned short* a3b = (unsigned short*)alloc(BIG * 2);
  unsigned short* t0b = (unsigned short*)alloc(BIG * 2);
  unsigned short* t1b = (unsigned short*)alloc(BIG * 2);
  unsigned short* t2b = (unsigned short*)alloc(BIG * 2);
  unsigned short* d1b = (unsigned short*)alloc(BIG * 2);
  unsigned short* d2b = (unsigned short*)alloc(BIG * 2);
  unsigned short* d3b = (unsigned short*)alloc(SML * 2);
  unsigned short* Wb[7];
  for (int i = 0; i < 7; ++i) Wb[i] = (unsigned short*)alloc(wN[i] * 2);

  // split-K partials for the N=1024 legs
  const size_t PS = SML * 4;  // 8 MB per plane
  int KS = 1;
  if (ws_size >= off + 4 * PS) KS = 4;
  else if (ws_size >= off + 2 * PS) KS = 2;
  float* psum = (KS > 1) ? (float*)alloc((size_t)KS * PS) : nullptr;

  // ---- conversions: one batched launch ----
  CvtJobs J;
  for (int i = 0; i < 7; ++i) { J.src[i] = wSrc[i]; J.dst[i] = Wb[i]; J.n4[i] = (int)(wN[i] >> 2); }
  J.src[7] = x; J.dst[7] = xb; J.n4[7] = (int)(SML >> 2);
  k_cvt8<<<dim3(2048, 8), 256, 0, stream>>>(J);

  float* out = (float*)d_out;
  const int n4_sml = (int)(SML >> 2);
  auto desc = [&](const unsigned short* A, const unsigned short* W_, int K, int knt,
                  int N, int mode, unsigned short* o0, unsigned short* o1,
                  unsigned short* o2, const unsigned short* i0, const float* targ,
                  float* fout) {
    GDesc g; g.A = A; g.W = W_; g.o0 = o0; g.o1 = o1; g.o2 = o2; g.i0 = i0;
    g.targ = targ; g.fout = fout; g.K = K; g.knt = knt; g.N = N; g.mode = mode;
    return g;
  };
  auto sig_standalone = [&](const unsigned short* A) {
    if (KS > 1) {
      GDesc g = desc(A, Wb[3], 4096, 64 / KS, 1024, M_PART,
                     nullptr, nullptr, nullptr, nullptr, nullptr, psum);
      gemm128<<<dim3(8, 16 * KS, 1), 256, 0, stream>>>(g, g, g);
      k_comb<<<2048, 256, 0, stream>>>(psum, target, d3b, out, n4_sml, KS);
    } else {
      GDesc g = desc(A, Wb[3], 4096, 64, 1024, M_SIG,
                     d3b, nullptr, nullptr, nullptr, target, out);
      gemm128<<<dim3(8, 16, 1), 256, 0, stream>>>(g, g, g);
    }
  };

  // ---- initial feedforward (gemm128: sequential chain) ----
  {
    GDesc g0 = desc(xb,  Wb[0], 1024, 16, 4096, M_ACT,  t0b, a1b, nullptr, nullptr, nullptr, nullptr);
    gemm128<<<dim3(32, 16, 1), 256, 0, stream>>>(g0, g0, g0);
    GDesc g1 = desc(a1b, Wb[1], 4096, 64, 4096, M_ACTD, t1b, a2b, d1b, nullptr, nullptr, nullptr);
    gemm128<<<dim3(32, 16, 1), 256, 0, stream>>>(g1, g1, g1);
    GDesc g2 = desc(a2b, Wb[2], 4096, 64, 4096, M_ACTD, t2b, a3b, d2b, nullptr, nullptr, nullptr);
    gemm128<<<dim3(32, 16, 1), 256, 0, stream>>>(g2, g2, g2);
    sig_standalone(a3b);
  }

  // ---- 5 inference iterations (gemmW pairs; dead-leg pruning) ----
  for (int it = 1; it <= 5; ++it) {
    GDesc e0 = desc(d1b, Wb[4], 4096, 64, 4096, M_ERR, a1b, nullptr, nullptr, t0b, nullptr, nullptr);
    GDesc e1 = desc(d2b, Wb[5], 4096, 64, 4096, M_ERR, a2b, nullptr, nullptr, t1b, nullptr, nullptr);
    GDesc e2 = desc(d3b, Wb[6], 1024, 16, 4096, M_ERR, a3b, nullptr, nullptr, t2b, nullptr, nullptr);
    GDesc p0 = desc(a1b, Wb[1], 4096, 64, 4096, M_PRED, t1b, d1b, nullptr, a2b, nullptr, nullptr);
    GDesc p1 = desc(a2b, Wb[2], 4096, 64, 4096, M_PRED, t2b, d2b, nullptr, a3b, nullptr, nullptr);
    if (it <= 3) {
      gemmW<<<dim3(8, 16, 2), 512, 0, stream>>>(e0, e1);          // 512 blk = 2/CU
      gemm128<<<dim3(32, 16, 1), 256, 0, stream>>>(e2, e2, e2);   // K=1024
      gemmW<<<dim3(8, 16, 2), 512, 0, stream>>>(p0, p1);          // after e2 (p1 reads a3)
      sig_standalone(a3b);
    } else if (it == 4) {
      // e0 dead (a1_4 only feeds dead p0_4); p0 dead (t1_4/d1_4 feed dead legs)
      gemmW<<<dim3(8, 16, 1), 512, 0, stream>>>(e1, e1);          // z=1: only d0 runs
      gemm128<<<dim3(32, 16, 1), 256, 0, stream>>>(e2, e2, e2);
      gemmW<<<dim3(8, 16, 1), 512, 0, stream>>>(p1, p1);          // z=1: only d0 runs
      sig_standalone(a3b);
    } else {
      // iter 5: only a3 update + final output leg live
      gemm128<<<dim3(32, 16, 1), 256, 0, stream>>>(e2, e2, e2);
      sig_standalone(a3b);
    }
  }
}